// Round 5
// baseline (38341.718 us; speedup 1.0000x reference)
//
#include <hip/hip_runtime.h>
#include <math.h>
#include <stddef.h>

#define BB 256
#define TT 512
#define IND 256
#define HH 1024
#define KV 1280                  // virtual K = 256 (x) + 1024 (h)
#define NCH 40                   // K-chunks of 32
#define XCH 8                    // chunks 0..7 are x-part

typedef __attribute__((ext_vector_type(8))) short short8;
typedef __attribute__((ext_vector_type(4))) float f32x4;
#define MFMA __builtin_amdgcn_mfma_f32_16x16x32_bf16

typedef __attribute__((address_space(1))) const unsigned char gconst_b;
typedef __attribute__((address_space(3))) unsigned char lds_b;

union U16 { unsigned long long u[2]; short8 s; };

// ---- fp32 -> 3-term bf16 split (v ~= hi+mid+lo, rel err ~2^-26) ------------
__device__ __forceinline__ unsigned short bf16_rne(float f) {
  unsigned u = __builtin_bit_cast(unsigned, f);
  u += 0x7FFFu + ((u >> 16) & 1u);
  return (unsigned short)(u >> 16);
}
__device__ __forceinline__ float bf16_f(unsigned short h) {
  unsigned u = ((unsigned)h) << 16;
  return __builtin_bit_cast(float, u);
}
__device__ __forceinline__ void split3(float v, unsigned short& hi,
                                       unsigned short& mi, unsigned short& lo) {
  hi = bf16_rne(v);
  float r = v - bf16_f(hi);
  mi = bf16_rne(r);
  float r2 = r - bf16_f(mi);
  lo = bf16_rne(r2);
}

// ---- prep: Wcat[p][col][kv]  kv<256 -> Wx[col][kv], else Wh[col][kv-256] ---
__global__ __launch_bounds__(256) void split_wcat(
    const float* __restrict__ Wx, const float* __restrict__ Wh,
    unsigned short* __restrict__ Wc)
{
  const int col = blockIdx.y;                     // 0..3071
  const int kv  = blockIdx.x * 256 + threadIdx.x; // 0..1279
  const float v = (kv < IND) ? Wx[(size_t)col * IND + kv]
                             : Wh[(size_t)col * HH + (kv - IND)];
  unsigned short a, b, c;
  split3(v, a, b, c);
  const size_t o = (size_t)col * KV + kv;
  const size_t ps = (size_t)3072 * KV;
  Wc[o] = a; Wc[o + ps] = b; Wc[o + 2 * ps] = c;
}

// ---- init: h0 = 0 (fp32 plane + 3 bf16 planes) + barrier counter = 0 -------
__global__ __launch_bounds__(256) void init_h(
    float* __restrict__ hf, unsigned short* __restrict__ ht,
    unsigned* __restrict__ cnt)
{
  const int i = blockIdx.x * 256 + threadIdx.x;   // 262144 total
  hf[i] = 0.f;
  ht[i] = 0; ht[i + BB * HH] = 0; ht[i + 2 * BB * HH] = 0;
  if (i == 0) *cnt = 0u;
}

// ---------------------------------------------------------------------------
// gru_persist: ALL 512 steps in ONE cooperative dispatch.
// 256 blocks (1/CU) x 256 thr (4 waves). Per step: R4 body (B dbuf-staged in
// LDS via global_load_lds, A direct->reg, fused gate epilogue), then a custom
// grid barrier. Cross-XCD h coherence: h stores normal + RELEASE fence
// (buffer_wbl2 -> L3) before arrive; h loads agent-scope (sc1, bypass stale
// L2). NO L2 invalidate anywhere -> weights stay L2-resident all 512 steps.
// ---------------------------------------------------------------------------
__global__ __launch_bounds__(256, 1) void gru_persist(
    const float* __restrict__ x,
    const unsigned short* __restrict__ Wc,     // [3][3072][1280]
    const float* __restrict__ bx, const float* __restrict__ bh,
    float* __restrict__ hf0, float* __restrict__ hf1,
    unsigned short* __restrict__ ht0, unsigned short* __restrict__ ht1,
    unsigned* __restrict__ cnt)
{
  __shared__ unsigned short Bs[2 * 4608];      // 2 x 9KB

  const int id  = blockIdx.x;
  const int xcd = id & 7;
  const int sub = id >> 3;
  const int jt  = xcd * 8 + (sub & 7);         // 0..63  (h-col tile)
  const int mt  = sub >> 3;                    // 0..3   (row tile)

  const int tid  = threadIdx.x;
  const int lane = tid & 63;
  const int wv   = tid >> 6;
  const int l15  = lane & 15;
  const int lko  = lane >> 4;                  // k-octet 0..3
  const int r0   = mt * 64 + wv * 16;
  const int jj0  = jt * 16;

  const size_t wps = (size_t)3072 * KV;        // W plane stride
  const size_t hps = (size_t)BB * HH;          // h plane stride

  // hoisted biases (per lane's output column)
  const int jj = jj0 + l15;
  const float bxr = bx[jj],          bhr = bh[jj];
  const float bxz = bx[HH + jj],     bhz = bh[HH + jj];
  const float bxn = bx[2 * HH + jj], bhn = bh[2 * HH + jj];

#define STAGE(KC, BUF)                                                         \
  if (wv < 3) {                                                                \
    const unsigned short* wp_ = Wc + (size_t)wv * wps;                         \
    _Pragma("unroll")                                                          \
    for (int g = 0; g < 3; ++g) {                                              \
      const unsigned short* src_ =                                             \
          wp_ + (size_t)(g * HH + jj0 + l15) * KV + (KC) * 32 + lko * 8;       \
      __builtin_amdgcn_global_load_lds(                                        \
          (const gconst_b*)src_,                                               \
          (lds_b*)&Bs[(BUF) * 4608 + (wv * 3 + g) * 512], 16, 0, 0);           \
    }                                                                          \
  }

#define LOADA_H(KC, AH, AM, AL)                                                \
  {                                                                            \
    const unsigned short* hb_ =                                                \
        htc + (size_t)(r0 + l15) * HH + ((KC) - XCH) * 32 + lko * 8;           \
    const unsigned long long* q0_ = (const unsigned long long*)hb_;            \
    const unsigned long long* q1_ = (const unsigned long long*)(hb_ + hps);    \
    const unsigned long long* q2_ = (const unsigned long long*)(hb_ + 2*hps);  \
    U16 t0_, t1_, t2_;                                                         \
    t0_.u[0] = __hip_atomic_load(q0_,   __ATOMIC_RELAXED, __HIP_MEMORY_SCOPE_AGENT); \
    t0_.u[1] = __hip_atomic_load(q0_+1, __ATOMIC_RELAXED, __HIP_MEMORY_SCOPE_AGENT); \
    t1_.u[0] = __hip_atomic_load(q1_,   __ATOMIC_RELAXED, __HIP_MEMORY_SCOPE_AGENT); \
    t1_.u[1] = __hip_atomic_load(q1_+1, __ATOMIC_RELAXED, __HIP_MEMORY_SCOPE_AGENT); \
    t2_.u[0] = __hip_atomic_load(q2_,   __ATOMIC_RELAXED, __HIP_MEMORY_SCOPE_AGENT); \
    t2_.u[1] = __hip_atomic_load(q2_+1, __ATOMIC_RELAXED, __HIP_MEMORY_SCOPE_AGENT); \
    AH = t0_.s; AM = t1_.s; AL = t2_.s;                                        \
  }

#define LOADA_X(KC, AH, AM, AL)                                                \
  {                                                                            \
    const float* xb_ = x + ((size_t)(r0 + l15) * TT + t) * IND + (KC) * 32     \
                         + lko * 8;                                            \
    float xv_[8];                                                              \
    *reinterpret_cast<float4*>(&xv_[0]) =                                      \
        *reinterpret_cast<const float4*>(xb_);                                 \
    *reinterpret_cast<float4*>(&xv_[4]) =                                      \
        *reinterpret_cast<const float4*>(xb_ + 4);                             \
    _Pragma("unroll")                                                          \
    for (int e_ = 0; e_ < 8; ++e_) {                                           \
      unsigned short h_, m_, l_;                                               \
      split3(xv_[e_], h_, m_, l_);                                             \
      AH[e_] = (short)h_; AM[e_] = (short)m_; AL[e_] = (short)l_;              \
    }                                                                          \
  }

  for (int t = 0; t < TT; ++t) {
    const float* hfc          = (t & 1) ? hf1 : hf0;
    float* hfn                = (t & 1) ? hf0 : hf1;
    const unsigned short* htc = (t & 1) ? ht1 : ht0;
    unsigned short* htn       = (t & 1) ? ht0 : ht1;

    f32x4 aR0 = {0,0,0,0}, aR1 = {0,0,0,0};
    f32x4 aZ0 = {0,0,0,0}, aZ1 = {0,0,0,0};
    f32x4 aNx0 = {0,0,0,0}, aNx1 = {0,0,0,0};
    f32x4 aNh0 = {0,0,0,0}, aNh1 = {0,0,0,0};

    short8 cah, cam, cal, nah, nam, nal;

    STAGE(0, 0)
    LOADA_X(0, cah, cam, cal)

    for (int kc = 0; kc < NCH; ++kc) {
      __syncthreads();             // stage(kc) landed; prev reads done
      const int nk = kc + 1;
      if (nk < NCH) {
        STAGE(nk, nk & 1)
        if (nk < XCH) { LOADA_X(nk, nah, nam, nal) }
        else          { LOADA_H(nk, nah, nam, nal) }
      }

      const int bb = (kc & 1) * 4608;
      const int fo = lko * 128 + l15 * 8;
      #pragma unroll
      for (int g = 0; g < 3; ++g) {
        const short8 bh_ = *reinterpret_cast<const short8*>(&Bs[bb + g * 512 + fo]);
        const short8 bm_ = *reinterpret_cast<const short8*>(&Bs[bb + (3 + g) * 512 + fo]);
        const short8 bl_ = *reinterpret_cast<const short8*>(&Bs[bb + (6 + g) * 512 + fo]);
        f32x4 *p0, *p1;
        if (g == 0)        { p0 = &aR0;  p1 = &aR1; }
        else if (g == 1)   { p0 = &aZ0;  p1 = &aZ1; }
        else if (kc < XCH) { p0 = &aNx0; p1 = &aNx1; }
        else               { p0 = &aNh0; p1 = &aNh1; }
        *p0 = MFMA(cah, bh_, *p0, 0, 0, 0);
        *p1 = MFMA(cah, bm_, *p1, 0, 0, 0);
        *p0 = MFMA(cam, bh_, *p0, 0, 0, 0);
        *p1 = MFMA(cah, bl_, *p1, 0, 0, 0);
        *p0 = MFMA(cam, bm_, *p0, 0, 0, 0);
        *p1 = MFMA(cal, bh_, *p1, 0, 0, 0);
      }
      cah = nah; cam = nam; cal = nal;
    }

    // ---- fused gate epilogue (C: col = lane&15, row = (lane>>4)*4 + reg) ----
    #pragma unroll
    for (int i = 0; i < 4; ++i) {
      const int row = r0 + lko * 4 + i;
      const float sr = aR0[i] + aR1[i] + bxr + bhr;
      const float sz = aZ0[i] + aZ1[i] + bxz + bhz;
      const float xn = aNx0[i] + aNx1[i] + bxn;
      const float hn = aNh0[i] + aNh1[i] + bhn;
      const float r  = 1.f / (1.f + __expf(-sr));
      const float z  = 1.f / (1.f + __expf(-sz));
      const float n  = tanhf(xn + r * hn);
      const unsigned hu = __hip_atomic_load(
          (const unsigned*)&hfc[(size_t)row * HH + jj],
          __ATOMIC_RELAXED, __HIP_MEMORY_SCOPE_AGENT);
      const float hp = __builtin_bit_cast(float, hu);
      const float hv = (1.f - z) * hp + z * n;  // nonstandard update (per ref)
      hfn[(size_t)row * HH + jj] = hv;
      unsigned short th, tm, tl;
      split3(hv, th, tm, tl);
      htn[(size_t)row * HH + jj] = th;
      htn[hps + (size_t)row * HH + jj] = tm;
      htn[2 * hps + (size_t)row * HH + jj] = tl;
    }

    // ---- grid barrier: release (wbl2 -> L3) + arrive + spin ----
    __syncthreads();               // all waves' stores drained to L2
    if (tid == 0) {
      __builtin_amdgcn_fence(__ATOMIC_RELEASE, "agent");
      __hip_atomic_fetch_add(cnt, 1u, __ATOMIC_RELEASE,
                             __HIP_MEMORY_SCOPE_AGENT);
      const unsigned tgt = 256u * (unsigned)(t + 1);
      while (__hip_atomic_load(cnt, __ATOMIC_RELAXED,
                               __HIP_MEMORY_SCOPE_AGENT) < tgt)
        __builtin_amdgcn_s_sleep(2);
    }
    __syncthreads();
  }
#undef STAGE
#undef LOADA_H
#undef LOADA_X
}

// ---------------------------------------------------------------------------
// final_gemm: out[b,o] = h[b,:] . Wf[o,:] + bf[o]   (256x256x1024, runs once)
// ---------------------------------------------------------------------------
__global__ __launch_bounds__(256) void final_gemm(
    const float* __restrict__ h, const float* __restrict__ Wf,
    const float* __restrict__ bf, float* __restrict__ out)
{
  __shared__ float As[32][36];
  __shared__ float Ws[32][36];
  const int tid = threadIdx.x;
  const int b0 = blockIdx.x * 32, o0 = blockIdx.y * 32;
  const int to = tid & 31, tb = tid >> 5;
  float acc[4] = {};
  for (int kc = 0; kc < HH; kc += 32) {
    __syncthreads();
    #pragma unroll
    for (int p = 0; p < 4; ++p) {
      const int f = tid + 256 * p;
      const int row = f >> 5, c = f & 31;
      As[c][row] = h[(size_t)(b0 + row) * HH + kc + c];
      Ws[c][row] = Wf[(size_t)(o0 + row) * HH + kc + c];
    }
    __syncthreads();
    #pragma unroll
    for (int c = 0; c < 32; ++c) {
      const float4 a = *reinterpret_cast<const float4*>(&As[c][tb * 4]);
      const float w = Ws[c][to];
      acc[0] += a.x * w; acc[1] += a.y * w; acc[2] += a.z * w; acc[3] += a.w * w;
    }
  }
  #pragma unroll
  for (int i = 0; i < 4; ++i)
    out[(size_t)(b0 + tb * 4 + i) * 256 + o0 + to] = acc[i] + bf[o0 + to];
}

// ---------------------------------------------------------------------------
extern "C" void kernel_launch(void* const* d_in, const int* in_sizes, int n_in,
                              void* d_out, int out_size, void* d_ws, size_t ws_size,
                              hipStream_t stream)
{
  const float* x  = (const float*)d_in[0];
  const float* Wx = (const float*)d_in[1];
  const float* bx = (const float*)d_in[2];
  const float* Wh = (const float*)d_in[3];
  const float* bh = (const float*)d_in[4];
  const float* Wf = (const float*)d_in[5];
  const float* bf = (const float*)d_in[6];
  float* out = (float*)d_out;

  // ws layout (~28.7 MB):
  //   hf0, hf1                 : 2 x 262144 f32
  //   Wc  [3][3072][1280] bf16 : 11,796,480 ush
  //   ht0, ht1 [3][256][1024]  : 2 x 786,432 ush
  //   cnt                      : 1 u32 (grid barrier)
  float* wsf = (float*)d_ws;
  float* hf0 = wsf;
  float* hf1 = wsf + (size_t)BB * HH;
  unsigned short* Wc  = (unsigned short*)(wsf + 2 * (size_t)BB * HH);
  unsigned short* ht0 = Wc + (size_t)3 * 3072 * KV;
  unsigned short* ht1 = ht0 + (size_t)3 * BB * HH;
  unsigned* cnt = (unsigned*)(ht1 + (size_t)3 * BB * HH);

  split_wcat<<<dim3(5, 3072), 256, 0, stream>>>(Wx, Wh, Wc);
  init_h<<<dim3(1024), 256, 0, stream>>>(hf0, ht0, cnt);

  void* kargs[] = {(void*)&x, (void*)&Wc, (void*)&bx, (void*)&bh,
                   (void*)&hf0, (void*)&hf1, (void*)&ht0, (void*)&ht1,
                   (void*)&cnt};
  hipLaunchCooperativeKernel(gru_persist, dim3(256), dim3(256), kargs, 0u,
                             stream);

  // t=511 (odd) writes hf0 -> final h is hf0
  final_gemm<<<dim3(8, 8), 256, 0, stream>>>(hf0, Wf, bf, out);
}